// Round 1
// baseline (1444.970 us; speedup 1.0000x reference)
//
#include <hip/hip_runtime.h>
#include <hip/hip_bf16.h>

typedef __bf16 bf16;
typedef __attribute__((ext_vector_type(8))) __bf16 bf16x8;
typedef __attribute__((ext_vector_type(4))) __bf16 bf16x4;
typedef __attribute__((ext_vector_type(2))) __bf16 bf16x2;
typedef __attribute__((ext_vector_type(4))) float  f32x4;

#define BN_EPS 1e-5f

// Tile config: BN=128 fixed, BK=32 (one 16x16x32 MFMA per K-tile), 256 threads.
// 2x2 waves; per-wave tile (BM/2) x 64.
constexpr int BK  = 32;
constexpr int BKP = 40;   // +8 bf16 pad: row stride 80B = 5 banks-of-16B -> frag reads ~2-way (free)
constexpr int BN  = 128;

// EPI: 0 = plain store, 1 = bias+ReLU, 2 = bias + BN affine (eval)
template<int BM, int EPI>
__global__ __launch_bounds__(256, 2)
void gemm_split(const float* __restrict__ A, const float* __restrict__ B,
                float* __restrict__ C, int M, int N, int K,
                const float* __restrict__ bias,
                const float* __restrict__ bn_g, const float* __restrict__ bn_b,
                const float* __restrict__ bn_m, const float* __restrict__ bn_v)
{
    constexpr int MT  = BM / 32;  // 16x16 m-frags per wave (BM/2/16)
    constexpr int NT  = 4;        // 64/16
    constexpr int ASW = BM / 32;  // A staging sweeps (32 rows each)

    __shared__ alignas(16) bf16 AsH[BM][BKP];
    __shared__ alignas(16) bf16 AsL[BM][BKP];
    __shared__ alignas(16) bf16 BsH[BN][BKP];   // stored transposed: [n][k]
    __shared__ alignas(16) bf16 BsL[BN][BKP];

    const int tid = threadIdx.x;
    const int l   = tid & 63;
    const int wid = tid >> 6;
    const int wr  = wid >> 1;
    const int wc  = wid & 1;

    const int m0 = blockIdx.y * BM;
    const int n0 = blockIdx.x * BN;

    // A staging: row = s*32 + (tid>>3), cols (tid&7)*4 .. +3   (float4, coalesced per row)
    const int arow = tid >> 3;
    const int acol = (tid & 7) * 4;
    // B staging: row-pair p = s*8 + (tid>>5) -> k = 2p,2p+1; cols (tid&31)*4 .. +3
    const int bp   = tid >> 5;
    const int bcol = (tid & 31) * 4;

    const float* Ap = A + (size_t)(m0 + arow) * K + acol;
    const float* Bp = B + (size_t)n0 + bcol;

    const int NKT = K / BK;

    f32x4 acc[MT][NT];
    #pragma unroll
    for (int i = 0; i < MT; ++i)
        #pragma unroll
        for (int j = 0; j < NT; ++j)
            acc[i][j] = f32x4{0.f, 0.f, 0.f, 0.f};

    f32x4 ar[ASW];
    f32x4 br0[2], br1[2];

    // prologue: load K-tile 0 into registers
    #pragma unroll
    for (int s = 0; s < ASW; ++s)
        ar[s] = *(const f32x4*)(Ap + (size_t)s * 32 * K);
    #pragma unroll
    for (int s = 0; s < 2; ++s) {
        const int k0 = 2 * (s * 8 + bp);
        br0[s] = *(const f32x4*)(Bp + (size_t)k0 * N);
        br1[s] = *(const f32x4*)(Bp + (size_t)(k0 + 1) * N);
    }

    for (int kt = 0; kt < NKT; ++kt) {
        // ---- split fp32 -> hi/lo bf16, write to LDS ----
        #pragma unroll
        for (int s = 0; s < ASW; ++s) {
            const int r = s * 32 + arow;
            bf16x4 h, lo;
            #pragma unroll
            for (int j = 0; j < 4; ++j) {
                const float f = ar[s][j];
                const bf16 hh = (bf16)f;
                h[j]  = hh;
                lo[j] = (bf16)(f - (float)hh);
            }
            *(bf16x4*)&AsH[r][acol] = h;
            *(bf16x4*)&AsL[r][acol] = lo;
        }
        #pragma unroll
        for (int s = 0; s < 2; ++s) {
            const int k0 = 2 * (s * 8 + bp);
            #pragma unroll
            for (int j = 0; j < 4; ++j) {
                const float f0 = br0[s][j], f1 = br1[s][j];
                const bf16 h0 = (bf16)f0, h1 = (bf16)f1;
                bf16x2 hh, ll;
                hh[0] = h0;                      hh[1] = h1;
                ll[0] = (bf16)(f0 - (float)h0);  ll[1] = (bf16)(f1 - (float)h1);
                *(bf16x2*)&BsH[bcol + j][k0] = hh;   // transposed store
                *(bf16x2*)&BsL[bcol + j][k0] = ll;
            }
        }
        __syncthreads();

        // ---- issue next-tile global loads; latency hides under MFMA below ----
        if (kt + 1 < NKT) {
            const float* An = Ap + (size_t)(kt + 1) * BK;
            #pragma unroll
            for (int s = 0; s < ASW; ++s)
                ar[s] = *(const f32x4*)(An + (size_t)s * 32 * K);
            const float* Bn = Bp + (size_t)(kt + 1) * BK * N;
            #pragma unroll
            for (int s = 0; s < 2; ++s) {
                const int k0 = 2 * (s * 8 + bp);
                br0[s] = *(const f32x4*)(Bn + (size_t)k0 * N);
                br1[s] = *(const f32x4*)(Bn + (size_t)(k0 + 1) * N);
            }
        }

        // ---- fragments + 3-product MFMA ----
        {
            const int kg  = (l >> 4) * 8;          // 8 consecutive k per lane-group
            const int ar0 = wr * (BM / 2) + (l & 15);
            const int bc0 = wc * 64 + (l & 15);
            bf16x8 aH[MT], aL[MT], bH[NT], bL[NT];
            #pragma unroll
            for (int i = 0; i < MT; ++i) {
                aH[i] = *(const bf16x8*)&AsH[ar0 + i * 16][kg];
                aL[i] = *(const bf16x8*)&AsL[ar0 + i * 16][kg];
            }
            #pragma unroll
            for (int j = 0; j < NT; ++j) {
                bH[j] = *(const bf16x8*)&BsH[bc0 + j * 16][kg];
                bL[j] = *(const bf16x8*)&BsL[bc0 + j * 16][kg];
            }
            #pragma unroll
            for (int i = 0; i < MT; ++i)
                #pragma unroll
                for (int j = 0; j < NT; ++j) {
                    acc[i][j] = __builtin_amdgcn_mfma_f32_16x16x32_bf16(aH[i], bH[j], acc[i][j], 0, 0, 0);
                    acc[i][j] = __builtin_amdgcn_mfma_f32_16x16x32_bf16(aH[i], bL[j], acc[i][j], 0, 0, 0);
                    acc[i][j] = __builtin_amdgcn_mfma_f32_16x16x32_bf16(aL[i], bH[j], acc[i][j], 0, 0, 0);
                }
        }
        __syncthreads();
    }

    // ---- epilogue: C/D mapping col = lane&15, row = (lane>>4)*4 + reg ----
    #pragma unroll
    for (int j = 0; j < NT; ++j) {
        const int c = n0 + wc * 64 + j * 16 + (l & 15);
        float bi = 0.f, sc = 1.f, sh = 0.f;
        if (EPI != 0) bi = bias[c];
        if (EPI == 2) {
            const float iv = bn_g[c] * rsqrtf(bn_v[c] + BN_EPS);
            sc = iv;
            sh = bn_b[c] - bn_m[c] * iv;
        }
        #pragma unroll
        for (int i = 0; i < MT; ++i) {
            const int r0 = m0 + wr * (BM / 2) + i * 16 + (l >> 4) * 4;
            #pragma unroll
            for (int q = 0; q < 4; ++q) {
                float v = acc[i][j][q] + bi;
                if (EPI == 1) v = fmaxf(v, 0.f);
                if (EPI == 2) v = v * sc + sh;
                C[(size_t)(r0 + q) * N + c] = v;
            }
        }
    }
}

extern "C" void kernel_launch(void* const* d_in, const int* in_sizes, int n_in,
                              void* d_out, int out_size, void* d_ws, size_t ws_size,
                              hipStream_t stream)
{
    const float* x    = (const float*)d_in[0];   // [8192,1024]
    const float* IF   = (const float*)d_in[1];   // [8192,8192]
    const float* adj  = (const float*)d_in[2];   // [8192,8192]
    const float* W1   = (const float*)d_in[3];   // [1024,512]
    const float* b1   = (const float*)d_in[4];   // [512]
    const float* W2   = (const float*)d_in[5];   // [512,256]
    const float* b2   = (const float*)d_in[6];   // [256]
    const float* bn_g = (const float*)d_in[7];
    const float* bn_b = (const float*)d_in[8];
    const float* bn_m = (const float*)d_in[9];
    const float* bn_v = (const float*)d_in[10];
    float* out = (float*)d_out;                  // [8192,256]

    constexpr int N = 8192, NF = 1024, NH = 512, OD = 256;

    float* support = (float*)d_ws;               // [8192,512]  16 MB
    float* H1      = support + (size_t)N * NH;   // [8192,512]  16 MB
    float* T       = H1 + (size_t)N * NH;        // [8192,256]   8 MB

    dim3 blk(256);

    // 1) support = x @ W1                         (M=8192, N=512, K=1024)
    gemm_split<128, 0><<<dim3(NH / BN, N / 128), blk, 0, stream>>>(
        x, W1, support, N, NH, NF, nullptr, nullptr, nullptr, nullptr, nullptr);

    // 2) H1 = relu(IFadj @ support + b1)          (M=8192, N=512, K=8192)
    gemm_split<128, 1><<<dim3(NH / BN, N / 128), blk, 0, stream>>>(
        IF, support, H1, N, NH, N, b1, nullptr, nullptr, nullptr, nullptr);

    // 3) T = H1 @ W2                              (M=8192, N=256, K=512)
    gemm_split<64, 0><<<dim3(OD / BN, N / 64), blk, 0, stream>>>(
        H1, W2, T, N, OD, NH, nullptr, nullptr, nullptr, nullptr, nullptr);

    // 4) out = BN(adj @ T + b2)                   (M=8192, N=256, K=8192)
    gemm_split<64, 2><<<dim3(OD / BN, N / 64), blk, 0, stream>>>(
        adj, T, out, N, OD, N, b2, bn_g, bn_b, bn_m, bn_v);
}

// Round 4
// 1040.562 us; speedup vs baseline: 1.3886x; 1.3886x over previous
//
#include <hip/hip_runtime.h>
#include <hip/hip_bf16.h>

typedef __bf16 bf16;
typedef __attribute__((ext_vector_type(8))) __bf16 bf16x8;
typedef __attribute__((ext_vector_type(4))) __bf16 bf16x4;
typedef __attribute__((ext_vector_type(4))) float  f32x4;

#define BN_EPS 1e-5f

constexpr int BK  = 32;   // K-tile (one 16x16x32 MFMA step)
constexpr int BKP = 40;   // padded row: 80B = 20 banks -> frag reads ~2-way
constexpr int BNT = 64;   // N-tile

// ---------------- tiled transpose: out[C][R] = in[R][C]^T ----------------
__global__ __launch_bounds__(256)
void transpose_f32(const float* __restrict__ in, float* __restrict__ out,
                   int R, int C)
{
    __shared__ float t[32][33];
    const int c0 = blockIdx.x * 32;
    const int r0 = blockIdx.y * 32;
    const int tx = threadIdx.x & 31;
    const int ty = threadIdx.x >> 5;         // 0..7
    #pragma unroll
    for (int s = 0; s < 4; ++s)
        t[ty + s * 8][tx] = in[(size_t)(r0 + ty + s * 8) * C + c0 + tx];
    __syncthreads();
    #pragma unroll
    for (int s = 0; s < 4; ++s)
        out[(size_t)(c0 + ty + s * 8) * R + r0 + tx] = t[tx][ty + s * 8];
}

// ---------------- GEMM: C = A[M][K] x Bt[N][K]^T, split-bf16 3-product ----
// EPI: 0 = none, 1 = bias+ReLU, 2 = bias + BN affine.  WT: write C^T [N][M].
template<int BM, int EPI, bool WT>
__global__ __launch_bounds__(256, 2)
void gemm_bt(const float* __restrict__ A, const float* __restrict__ Bt,
             float* __restrict__ C, int M, int N, int K,
             const float* __restrict__ bias,
             const float* __restrict__ bn_g, const float* __restrict__ bn_b,
             const float* __restrict__ bn_m, const float* __restrict__ bn_v)
{
    constexpr int MT  = BM / 32;   // 16x16 m-frags per wave (wave tile (BM/2) x 32)
    constexpr int NT  = 2;
    constexpr int ASW = BM / 32;   // A staging sweeps (32 rows x 32 cols each)
    constexpr int BSW = 2;

    __shared__ alignas(16) bf16 AsH[BM][BKP];
    __shared__ alignas(16) bf16 AsL[BM][BKP];
    __shared__ alignas(16) bf16 BsH[BNT][BKP];
    __shared__ alignas(16) bf16 BsL[BNT][BKP];

    const int tid = threadIdx.x;
    const int l   = tid & 63;
    const int wid = tid >> 6;
    const int wr  = wid >> 1;      // 0..1
    const int wc  = wid & 1;       // 0..1

    const int m0 = blockIdx.y * BM;
    const int n0 = blockIdx.x * BNT;

    // staging: row = sweep*32 + (tid>>3), cols (tid&7)*4 .. +3  (float4, coalesced)
    const int srow = tid >> 3;           // 0..31
    const int scol = (tid & 7) * 4;      // 0,4,..,28

    const float* Ap = A  + (size_t)(m0 + srow) * K + scol;
    const float* Bp = Bt + (size_t)(n0 + srow) * K + scol;

    const int NKT = K / BK;

    f32x4 acc[MT][NT];
    #pragma unroll
    for (int i = 0; i < MT; ++i)
        #pragma unroll
        for (int j = 0; j < NT; ++j)
            acc[i][j] = f32x4{0.f, 0.f, 0.f, 0.f};

    f32x4 ar[ASW], br[BSW];

    #pragma unroll
    for (int s = 0; s < ASW; ++s)
        ar[s] = *(const f32x4*)(Ap + (size_t)s * 32 * K);
    #pragma unroll
    for (int s = 0; s < BSW; ++s)
        br[s] = *(const f32x4*)(Bp + (size_t)s * 32 * K);

    for (int kt = 0; kt < NKT; ++kt) {
        // ---- split fp32 -> hi/lo bf16, store to LDS (k-contiguous rows) ----
        #pragma unroll
        for (int s = 0; s < ASW; ++s) {
            const int r = s * 32 + srow;
            bf16x4 h, lo;
            #pragma unroll
            for (int j = 0; j < 4; ++j) {
                const float f = ar[s][j];
                const bf16 hh = (bf16)f;
                h[j]  = hh;
                lo[j] = (bf16)(f - (float)hh);
            }
            *(bf16x4*)&AsH[r][scol] = h;
            *(bf16x4*)&AsL[r][scol] = lo;
        }
        #pragma unroll
        for (int s = 0; s < BSW; ++s) {
            const int r = s * 32 + srow;
            bf16x4 h, lo;
            #pragma unroll
            for (int j = 0; j < 4; ++j) {
                const float f = br[s][j];
                const bf16 hh = (bf16)f;
                h[j]  = hh;
                lo[j] = (bf16)(f - (float)hh);
            }
            *(bf16x4*)&BsH[r][scol] = h;
            *(bf16x4*)&BsL[r][scol] = lo;
        }
        __syncthreads();

        // ---- issue next-tile global loads; latency hides under MFMA ----
        if (kt + 1 < NKT) {
            const float* An = Ap + (size_t)(kt + 1) * BK;
            const float* Bn = Bp + (size_t)(kt + 1) * BK;
            #pragma unroll
            for (int s = 0; s < ASW; ++s)
                ar[s] = *(const f32x4*)(An + (size_t)s * 32 * K);
            #pragma unroll
            for (int s = 0; s < BSW; ++s)
                br[s] = *(const f32x4*)(Bn + (size_t)s * 32 * K);
        }

        // ---- fragments + 3-product MFMA ----
        {
            const int kg  = (l >> 4) * 8;              // 8 consecutive k per group
            const int ar0 = wr * (BM / 2) + (l & 15);
            const int br0 = wc * 32 + (l & 15);
            bf16x8 aH[MT], aL[MT], bH[NT], bL[NT];
            #pragma unroll
            for (int i = 0; i < MT; ++i) {
                aH[i] = *(const bf16x8*)&AsH[ar0 + i * 16][kg];
                aL[i] = *(const bf16x8*)&AsL[ar0 + i * 16][kg];
            }
            #pragma unroll
            for (int j = 0; j < NT; ++j) {
                bH[j] = *(const bf16x8*)&BsH[br0 + j * 16][kg];
                bL[j] = *(const bf16x8*)&BsL[br0 + j * 16][kg];
            }
            #pragma unroll
            for (int i = 0; i < MT; ++i)
                #pragma unroll
                for (int j = 0; j < NT; ++j) {
                    acc[i][j] = __builtin_amdgcn_mfma_f32_16x16x32_bf16(aH[i], bH[j], acc[i][j], 0, 0, 0);
                    acc[i][j] = __builtin_amdgcn_mfma_f32_16x16x32_bf16(aH[i], bL[j], acc[i][j], 0, 0, 0);
                    acc[i][j] = __builtin_amdgcn_mfma_f32_16x16x32_bf16(aL[i], bH[j], acc[i][j], 0, 0, 0);
                }
        }
        __syncthreads();
    }

    // ---- epilogue: C/D map col = lane&15, row = (lane>>4)*4 + q ----
    #pragma unroll
    for (int j = 0; j < NT; ++j) {
        const int c = n0 + wc * 32 + j * 16 + (l & 15);
        float bi = 0.f, sc = 1.f, sh = 0.f;
        if (EPI != 0) bi = bias[c];
        if (EPI == 2) {
            const float iv = bn_g[c] * rsqrtf(bn_v[c] + BN_EPS);
            sc = iv;
            sh = bn_b[c] - bn_m[c] * iv;
        }
        #pragma unroll
        for (int i = 0; i < MT; ++i) {
            const int r0 = m0 + wr * (BM / 2) + i * 16 + (l >> 4) * 4;
            if (WT) {
                // lane holds 4 consecutive rows at one col -> contiguous in C^T
                *(f32x4*)&C[(size_t)c * M + r0] = acc[i][j];
            } else {
                #pragma unroll
                for (int q = 0; q < 4; ++q) {
                    float v = acc[i][j][q] + bi;
                    if (EPI == 1) v = fmaxf(v, 0.f);
                    if (EPI == 2) v = v * sc + sh;
                    C[(size_t)(r0 + q) * N + c] = v;
                }
            }
        }
    }
}

extern "C" void kernel_launch(void* const* d_in, const int* in_sizes, int n_in,
                              void* d_out, int out_size, void* d_ws, size_t ws_size,
                              hipStream_t stream)
{
    const float* x    = (const float*)d_in[0];   // [8192,1024]
    const float* IF   = (const float*)d_in[1];   // [8192,8192]
    const float* adj  = (const float*)d_in[2];   // [8192,8192]
    const float* W1   = (const float*)d_in[3];   // [1024,512]
    const float* b1   = (const float*)d_in[4];   // [512]
    const float* W2   = (const float*)d_in[5];   // [512,256]
    const float* b2   = (const float*)d_in[6];   // [256]
    const float* bn_g = (const float*)d_in[7];
    const float* bn_b = (const float*)d_in[8];
    const float* bn_m = (const float*)d_in[9];
    const float* bn_v = (const float*)d_in[10];
    float* out = (float*)d_out;                  // [8192,256]

    constexpr int N = 8192, NF = 1024, NH = 512, OD = 256;

    // ws layout (floats), 40MB total with aliasing:
    float* supT = (float*)d_ws;                   // [512][8192]  @0      16MB
    float* H1   = supT + (size_t)NH * N;          // [8192][512]  @16MB   16MB
    float* Tt   = H1 + (size_t)N * NH;            // [256][8192]  @32MB    8MB
    float* W1t  = Tt;                             // [512][1024]  @32MB (dead after G1)
    float* W2t  = supT;                           // [256][512]   @0    (written after G2)

    dim3 blk(256);

    // T1: W1t = W1^T
    transpose_f32<<<dim3(NH / 32, NF / 32), blk, 0, stream>>>(W1, W1t, NF, NH);

    // G1: supT = (x @ W1)^T               M=8192 N=512 K=1024, grid 8x64=512
    gemm_bt<128, 0, true><<<dim3(NH / BNT, N / 128), blk, 0, stream>>>(
        x, W1t, supT, N, NH, NF, nullptr, nullptr, nullptr, nullptr, nullptr);

    // G2: H1 = relu(IFadj @ sup + b1)     M=8192 N=512 K=8192, grid 8x64=512
    gemm_bt<128, 1, false><<<dim3(NH / BNT, N / 128), blk, 0, stream>>>(
        IF, supT, H1, N, NH, N, b1, nullptr, nullptr, nullptr, nullptr);

    // T2: W2t = W2^T   (into supT space; supT dead after G2)
    transpose_f32<<<dim3(OD / 32, NH / 32), blk, 0, stream>>>(W2, W2t, NH, OD);

    // G3: Tt = (H1 @ W2)^T                M=8192 N=256 K=512, grid 4x128=512
    gemm_bt<64, 0, true><<<dim3(OD / BNT, N / 64), blk, 0, stream>>>(
        H1, W2t, Tt, N, OD, NH, nullptr, nullptr, nullptr, nullptr, nullptr);

    // G4: out = BN(adj @ T + b2)          M=8192 N=256 K=8192, grid 4x128=512
    gemm_bt<64, 2, false><<<dim3(OD / BNT, N / 64), blk, 0, stream>>>(
        adj, Tt, out, N, OD, N, b2, bn_g, bn_b, bn_m, bn_v);
}